// Round 8
// baseline (844.529 us; speedup 1.0000x reference)
//
#include <hip/hip_runtime.h>
#include <cstdint>
#include <cstddef>

#define B_DIM 8
#define NQ    1024
#define MK    1024
#define CD    640
#define INV_EPS 20.0f
#define EPS_OT  0.05f

typedef unsigned short u16;
typedef __attribute__((ext_vector_type(8))) short bf16x8;
typedef __attribute__((ext_vector_type(4))) float f32x4;

#define GLDS(gp, lp) __builtin_amdgcn_global_load_lds( \
    (const __attribute__((address_space(1))) void*)(gp), \
    (__attribute__((address_space(3))) void*)(lp), 16, 0, 0)

static __device__ __forceinline__ float wave_reduce_sum(float s) {
#pragma unroll
  for (int off = 32; off; off >>= 1) s += __shfl_xor(s, off, 64);
  return s;
}

static __device__ __forceinline__ u16 f2bf(float f) {
  uint32_t u = __float_as_uint(f);
  u += 0x7fff + ((u >> 16) & 1);     // RNE
  return (u16)(u >> 16);
}
static __device__ __forceinline__ unsigned pack2bf(float a, float b) {
  return (unsigned)f2bf(a) | ((unsigned)f2bf(b) << 16);
}

// Agent-scope (MALL-coherent, placement-independent) relaxed accesses.
static __device__ __forceinline__ void g_store(float* p, float v) {
  __hip_atomic_store(p, v, __ATOMIC_RELAXED, __HIP_MEMORY_SCOPE_AGENT);
}
static __device__ __forceinline__ float g_load(const float* p) {
  return __hip_atomic_load((float*)p, __ATOMIC_RELAXED, __HIP_MEMORY_SCOPE_AGENT);
}
static __device__ __forceinline__ void g_storeu(unsigned* p, unsigned v) {
  __hip_atomic_store(p, v, __ATOMIC_RELAXED, __HIP_MEMORY_SCOPE_AGENT);
}
static __device__ __forceinline__ unsigned g_loadu(const unsigned* p) {
  return __hip_atomic_load((unsigned*)p, __ATOMIC_RELAXED, __HIP_MEMORY_SCOPE_AGENT);
}

// ---------------------------------------------------------------------------
// Setup: detect mask dtype, build maskI, per-batch mu, w=1, zero ctrl block
// ---------------------------------------------------------------------------
__global__ void k_setup(const void* __restrict__ maskRaw, int* __restrict__ maskI,
                        float* __restrict__ muVal, float* __restrict__ w,
                        unsigned* __restrict__ ctrl)
{
  __shared__ int s_flag;
  __shared__ int s_cnt[B_DIM];
  const int tid = threadIdx.x;
  if (tid == 0) s_flag = 0;
  if (tid < B_DIM) s_cnt[tid] = 0;
  ctrl[tid] = 0u;
  __syncthreads();

  const unsigned char* mb = (const unsigned char*)maskRaw;
  int local = 0;
  for (int i = tid; i < B_DIM * MK; i += 1024)
    if ((i & 3) && mb[i]) local = 1;
  if (local) atomicOr(&s_flag, 1);
  __syncthreads();

  const int isByte = s_flag;
  const int* mi32 = (const int*)maskRaw;
  for (int i = tid; i < B_DIM * MK; i += 1024) {
    int v = isByte ? (int)mb[i] : mi32[i];
    v = v ? 1 : 0;
    maskI[i] = v;
    if (v) atomicAdd(&s_cnt[i >> 10], 1);
  }
  for (int i = tid; i < B_DIM * NQ; i += 1024) w[i] = 1.0f;
  __syncthreads();
  if (tid < B_DIM) {
    float c = (float)s_cnt[tid];
    muVal[tid] = (c > 0.f ? 1.0f / c : 1.0f / (float)MK) + 1e-8f;
  }
}

// ---------------------------------------------------------------------------
// fp32 -> bf16 conversion for xq, xk, xv, Wq, Wk
// ---------------------------------------------------------------------------
__global__ __launch_bounds__(256)
void k_cvt5(const float* __restrict__ x0, u16* __restrict__ d0,
            const float* __restrict__ x1, u16* __restrict__ d1,
            const float* __restrict__ x2, u16* __restrict__ d2,
            const float* __restrict__ x3, u16* __restrict__ d3,
            const float* __restrict__ x4, u16* __restrict__ d4)
{
  const int a = blockIdx.y;
  const float* s; u16* d; int n;
  if      (a == 0) { s = x0; d = d0; n = 8192 * CD; }
  else if (a == 1) { s = x1; d = d1; n = 8192 * CD; }
  else if (a == 2) { s = x2; d = d2; n = 8192 * CD; }
  else if (a == 3) { s = x3; d = d3; n = CD * CD; }
  else             { s = x4; d = d4; n = CD * CD; }
  const int i = (blockIdx.x * 256 + threadIdx.x) * 4;
  if (i >= n) return;
  const float4 v = *(const float4*)(s + i);
  *(ushort4*)(d + i) = make_ushort4(f2bf(v.x), f2bf(v.y), f2bf(v.z), f2bf(v.w));
}

// ---------------------------------------------------------------------------
// Ah = bf16(Wp @ Wv)
// ---------------------------------------------------------------------------
__global__ __launch_bounds__(256)
void k_combineA(const float* __restrict__ Wp, const float* __restrict__ Wv,
                u16* __restrict__ Ah)
{
  __shared__ float Ps[32][68];
  __shared__ float Vs[32][68];
  const int tid = threadIdx.x;
  const int c0 = blockIdx.x << 6, k0 = blockIdx.y << 6;
  const int ty = tid >> 4, tx = tid & 15;
  float acc[4][4];
#pragma unroll
  for (int i = 0; i < 4; ++i)
#pragma unroll
    for (int j = 0; j < 4; ++j) acc[i][j] = 0.f;

  for (int j0 = 0; j0 < CD; j0 += 32) {
    {
      const int c = tid >> 2, j4 = (tid & 3) << 3;
      const float* p = Wp + (size_t)(c0 + c) * CD + j0 + j4;
      float4 u0 = *(const float4*)p, u1 = *(const float4*)(p + 4);
      Ps[j4 + 0][c] = u0.x; Ps[j4 + 1][c] = u0.y; Ps[j4 + 2][c] = u0.z; Ps[j4 + 3][c] = u0.w;
      Ps[j4 + 4][c] = u1.x; Ps[j4 + 5][c] = u1.y; Ps[j4 + 6][c] = u1.z; Ps[j4 + 7][c] = u1.w;
    }
    {
      const int j = tid >> 3, k4 = (tid & 7) << 3;
      const float* p = Wv + (size_t)(j0 + j) * CD + k0 + k4;
      float4 u0 = *(const float4*)p, u1 = *(const float4*)(p + 4);
      *(float4*)&Vs[j][k4] = u0; *(float4*)&Vs[j][k4 + 4] = u1;
    }
    __syncthreads();
#pragma unroll
    for (int j = 0; j < 32; ++j) {
      float a[4], b[4];
      *(float4*)a = *(const float4*)&Ps[j][ty << 2];
      *(float4*)b = *(const float4*)&Vs[j][tx << 2];
#pragma unroll
      for (int i = 0; i < 4; ++i)
#pragma unroll
        for (int jj = 0; jj < 4; ++jj)
          acc[i][jj] = fmaf(a[i], b[jj], acc[i][jj]);
    }
    __syncthreads();
  }
#pragma unroll
  for (int i = 0; i < 4; ++i) {
    *(ushort4*)(Ah + (size_t)(c0 + (ty << 2) + i) * CD + k0 + (tx << 2)) =
      make_ushort4(f2bf(acc[i][0]), f2bf(acc[i][1]), f2bf(acc[i][2]), f2bf(acc[i][3]));
  }
}

// bvp[c] = sum_j Wp[c][j]*bv[j]
__global__ __launch_bounds__(256)
void k_bvp(const float* __restrict__ Wp, const float* __restrict__ bv,
           float* __restrict__ bvp)
{
  const int c = (blockIdx.x << 2) + (threadIdx.x >> 6);
  const int lane = threadIdx.x & 63;
  float s = 0.f;
  for (int j = lane; j < CD; j += 64) s = fmaf(Wp[(size_t)c * CD + j], bv[j], s);
  s = wave_reduce_sum(s);
  if (!lane) bvp[c] = s;
}

// ---------------------------------------------------------------------------
// MFMA NT GEMMs (unchanged)
// ---------------------------------------------------------------------------
__global__ __launch_bounds__(256)
void mfma_proj(const u16* __restrict__ xqh, const u16* __restrict__ xkh,
               const u16* __restrict__ xvh,
               const u16* __restrict__ Wqh, const u16* __restrict__ Wkh,
               const u16* __restrict__ Ah,
               const float* __restrict__ bq, const float* __restrict__ bk,
               const float* __restrict__ bvp,
               float* __restrict__ qb, float* __restrict__ kb,
               float* __restrict__ vp)
{
  __shared__ u16 As[128 * 32];
  __shared__ u16 Bs[128 * 32];
  const int mode = blockIdx.z;
  const u16* X     = (mode == 0) ? xqh : ((mode == 1) ? xkh : xvh);
  const u16* W     = (mode == 0) ? Wqh : ((mode == 1) ? Wkh : Ah);
  const float* bias= (mode == 0) ? bq  : ((mode == 1) ? bk  : bvp);
  float* outp      = (mode == 0) ? qb  : ((mode == 1) ? kb  : vp);

  const int tid = threadIdx.x, wave = tid >> 6, lane = tid & 63;
  const int row0 = blockIdx.x << 7, col0 = blockIdx.y << 7;

  const int rS = (wave << 5) + (lane >> 2);
  const int pc = lane & 3;
  const int kc0 = pc ^ ((rS >> 1) & 3);
  const int kc1 = pc ^ (((rS + 16) >> 1) & 3);
  const u16* gA0 = X + (size_t)(row0 + rS) * CD + (kc0 << 3);
  const u16* gA1 = X + (size_t)(row0 + rS + 16) * CD + (kc1 << 3);
  const u16* gB0 = W + (size_t)(col0 + rS) * CD + (kc0 << 3);
  const u16* gB1 = W + (size_t)(col0 + rS + 16) * CD + (kc1 << 3);
  u16* lA = As + (wave << 10);
  u16* lB = Bs + (wave << 10);

  const int wm0 = (wave & 1) << 6, wn0 = (wave >> 1) << 6;
  int aOff[4], bOff[4];
#pragma unroll
  for (int t = 0; t < 4; ++t) {
    const int ra = wm0 + (t << 4) + (lane & 15);
    aOff[t] = ra * 32 + (((lane >> 4) ^ ((ra >> 1) & 3)) << 3);
    const int rb = wn0 + (t << 4) + (lane & 15);
    bOff[t] = rb * 32 + (((lane >> 4) ^ ((rb >> 1) & 3)) << 3);
  }
  f32x4 acc[4][4];
#pragma unroll
  for (int i = 0; i < 4; ++i)
#pragma unroll
    for (int j = 0; j < 4; ++j) acc[i][j] = {0.f, 0.f, 0.f, 0.f};

  for (int k0 = 0; k0 < CD; k0 += 32) {
    __syncthreads();
    GLDS(gA0, lA); GLDS(gA1, lA + 512);
    GLDS(gB0, lB); GLDS(gB1, lB + 512);
    gA0 += 32; gA1 += 32; gB0 += 32; gB1 += 32;
    __syncthreads();
    bf16x8 a[4], b[4];
#pragma unroll
    for (int t = 0; t < 4; ++t) {
      a[t] = *(const bf16x8*)(As + aOff[t]);
      b[t] = *(const bf16x8*)(Bs + bOff[t]);
    }
#pragma unroll
    for (int i = 0; i < 4; ++i)
#pragma unroll
      for (int j = 0; j < 4; ++j)
        acc[i][j] = __builtin_amdgcn_mfma_f32_16x16x32_bf16(a[i], b[j], acc[i][j], 0, 0, 0);
  }

  float bv4[4];
  int ccs[4];
#pragma unroll
  for (int j = 0; j < 4; ++j) {
    ccs[j] = col0 + wn0 + (j << 4) + (lane & 15);
    bv4[j] = bias[ccs[j]];
  }
#pragma unroll
  for (int i = 0; i < 4; ++i) {
    const int rbase = row0 + wm0 + (i << 4) + ((lane >> 4) << 2);
#pragma unroll
    for (int r = 0; r < 4; ++r) {
      const int rr = rbase + r;
      const size_t orow = (mode == 0) ? ((size_t)(rr & 7) * NQ + (rr >> 3)) : (size_t)rr;
      float* op = outp + orow * CD;
#pragma unroll
      for (int j = 0; j < 4; ++j)
        op[ccs[j]] = acc[i][j][r] + bv4[j];
    }
  }
}

__global__ __launch_bounds__(256)
void mfma_sim(const u16* __restrict__ kbh, const u16* __restrict__ qbh,
              float* __restrict__ E)
{
  __shared__ u16 As[128 * 32];
  __shared__ u16 Bs[128 * 32];
  const int tid = threadIdx.x, wave = tid >> 6, lane = tid & 63;
  const int b = blockIdx.z;
  const int row0 = blockIdx.x << 7, col0 = blockIdx.y << 7;
  const u16* A = kbh + (size_t)b * MK * CD;
  const u16* B = qbh + (size_t)b * NQ * CD;

  const int rS = (wave << 5) + (lane >> 2);
  const int pc = lane & 3;
  const int kc0 = pc ^ ((rS >> 1) & 3);
  const int kc1 = pc ^ (((rS + 16) >> 1) & 3);
  const u16* gA0 = A + (size_t)(row0 + rS) * CD + (kc0 << 3);
  const u16* gA1 = A + (size_t)(row0 + rS + 16) * CD + (kc1 << 3);
  const u16* gB0 = B + (size_t)(col0 + rS) * CD + (kc0 << 3);
  const u16* gB1 = B + (size_t)(col0 + rS + 16) * CD + (kc1 << 3);
  u16* lA = As + (wave << 10);
  u16* lB = Bs + (wave << 10);

  const int wm0 = (wave & 1) << 6, wn0 = (wave >> 1) << 6;
  int aOff[4], bOff[4];
#pragma unroll
  for (int t = 0; t < 4; ++t) {
    const int ra = wm0 + (t << 4) + (lane & 15);
    aOff[t] = ra * 32 + (((lane >> 4) ^ ((ra >> 1) & 3)) << 3);
    const int rb = wn0 + (t << 4) + (lane & 15);
    bOff[t] = rb * 32 + (((lane >> 4) ^ ((rb >> 1) & 3)) << 3);
  }
  f32x4 acc[4][4];
#pragma unroll
  for (int i = 0; i < 4; ++i)
#pragma unroll
    for (int j = 0; j < 4; ++j) acc[i][j] = {0.f, 0.f, 0.f, 0.f};

  for (int k0 = 0; k0 < CD; k0 += 32) {
    __syncthreads();
    GLDS(gA0, lA); GLDS(gA1, lA + 512);
    GLDS(gB0, lB); GLDS(gB1, lB + 512);
    gA0 += 32; gA1 += 32; gB0 += 32; gB1 += 32;
    __syncthreads();
    bf16x8 a[4], b[4];
#pragma unroll
    for (int t = 0; t < 4; ++t) {
      a[t] = *(const bf16x8*)(As + aOff[t]);
      b[t] = *(const bf16x8*)(Bs + bOff[t]);
    }
#pragma unroll
    for (int i = 0; i < 4; ++i)
#pragma unroll
      for (int j = 0; j < 4; ++j)
        acc[i][j] = __builtin_amdgcn_mfma_f32_16x16x32_bf16(a[i], b[j], acc[i][j], 0, 0, 0);
  }

#pragma unroll
  for (int i = 0; i < 4; ++i) {
    const int rbase = row0 + wm0 + (i << 4) + ((lane >> 4) << 2);
#pragma unroll
    for (int r = 0; r < 4; ++r) {
      const int rr = rbase + r;
      float* erow = E + (((size_t)(b << 10) + rr) << 10);
#pragma unroll
      for (int j = 0; j < 4; ++j) {
        const int cc = col0 + wn0 + (j << 4) + (lane & 15);
        erow[cc] = __expf((acc[i][j][r] - 1.f) * INV_EPS);
      }
    }
  }
}

__global__ __launch_bounds__(256)
void mfma_x(const u16* __restrict__ Et, const u16* __restrict__ Vpt,
            const float* __restrict__ w, const float* __restrict__ bp,
            float* __restrict__ out)
{
  __shared__ u16 As[128 * 32];
  __shared__ u16 Bs[128 * 32];
  const int tid = threadIdx.x, wave = tid >> 6, lane = tid & 63;
  const int b = blockIdx.z;
  const int row0 = blockIdx.x << 7;
  const int col0 = blockIdx.y << 7;
  const u16* A = Et + ((size_t)b << 20);
  const u16* B = Vpt + (size_t)b * CD * MK;

  const int rS = (wave << 5) + (lane >> 2);
  const int pc = lane & 3;
  const int kc0 = pc ^ ((rS >> 1) & 3);
  const int kc1 = pc ^ (((rS + 16) >> 1) & 3);
  const u16* gA0 = A + ((size_t)(row0 + rS) << 10) + (kc0 << 3);
  const u16* gA1 = A + ((size_t)(row0 + rS + 16) << 10) + (kc1 << 3);
  const u16* gB0 = B + ((size_t)(col0 + rS) << 10) + (kc0 << 3);
  const u16* gB1 = B + ((size_t)(col0 + rS + 16) << 10) + (kc1 << 3);
  u16* lA = As + (wave << 10);
  u16* lB = Bs + (wave << 10);

  const int wm0 = (wave & 1) << 6, wn0 = (wave >> 1) << 6;
  int aOff[4], bOff[4];
#pragma unroll
  for (int t = 0; t < 4; ++t) {
    const int ra = wm0 + (t << 4) + (lane & 15);
    aOff[t] = ra * 32 + (((lane >> 4) ^ ((ra >> 1) & 3)) << 3);
    const int rb = wn0 + (t << 4) + (lane & 15);
    bOff[t] = rb * 32 + (((lane >> 4) ^ ((rb >> 1) & 3)) << 3);
  }
  f32x4 acc[4][4];
#pragma unroll
  for (int i = 0; i < 4; ++i)
#pragma unroll
    for (int j = 0; j < 4; ++j) acc[i][j] = {0.f, 0.f, 0.f, 0.f};

  for (int k0 = 0; k0 < MK; k0 += 32) {
    __syncthreads();
    GLDS(gA0, lA); GLDS(gA1, lA + 512);
    GLDS(gB0, lB); GLDS(gB1, lB + 512);
    gA0 += 32; gA1 += 32; gB0 += 32; gB1 += 32;
    __syncthreads();
    bf16x8 a[4], b[4];
#pragma unroll
    for (int t = 0; t < 4; ++t) {
      a[t] = *(const bf16x8*)(As + aOff[t]);
      b[t] = *(const bf16x8*)(Bs + bOff[t]);
    }
#pragma unroll
    for (int i = 0; i < 4; ++i)
#pragma unroll
      for (int j = 0; j < 4; ++j)
        acc[i][j] = __builtin_amdgcn_mfma_f32_16x16x32_bf16(a[i], b[j], acc[i][j], 0, 0, 0);
  }

  float bv4[4];
  int ccs[4];
#pragma unroll
  for (int j = 0; j < 4; ++j) {
    ccs[j] = col0 + wn0 + (j << 4) + (lane & 15);
    bv4[j] = bp[ccs[j]];
  }
#pragma unroll
  for (int i = 0; i < 4; ++i) {
    const int rbase = row0 + wm0 + (i << 4) + ((lane >> 4) << 2);
#pragma unroll
    for (int r = 0; r < 4; ++r) {
      const int rr = rbase + r;
      const float wn = w[(b << 10) + rr];
      float* op = out + ((size_t)rr * 8 + b) * CD;
#pragma unroll
      for (int j = 0; j < 4; ++j)
        op[ccs[j]] = acc[i][j][r] * wn + bv4[j];
    }
  }
}

// ---------------------------------------------------------------------------
// l2norm rows of 640 fp32 -> bf16 output (single launch covers qb|kb)
// ---------------------------------------------------------------------------
__global__ __launch_bounds__(256)
void k_l2bf(const float* __restrict__ X, u16* __restrict__ O)
{
  const int row = (blockIdx.x << 2) + (threadIdx.x >> 6);
  const int lane = threadIdx.x & 63;
  const float2* p2 = (const float2*)(X + (size_t)row * CD);
  float2 v[5];
  float ss = 0.f;
#pragma unroll
  for (int i = 0; i < 5; ++i) {
    v[i] = p2[lane + (i << 6)];
    ss = fmaf(v[i].x, v[i].x, fmaf(v[i].y, v[i].y, ss));
  }
  ss = wave_reduce_sum(ss);
  const float inv = 1.0f / fmaxf(sqrtf(ss), 1e-12f);
  ushort2* o2 = (ushort2*)(O + (size_t)row * CD);
#pragma unroll
  for (int i = 0; i < 5; ++i)
    o2[lane + (i << 6)] = make_ushort2(f2bf(v[i].x * inv), f2bf(v[i].y * inv));
}

// ---------------------------------------------------------------------------
// Vp transpose (unchanged)
// ---------------------------------------------------------------------------
__global__ __launch_bounds__(256)
void k_vpt(const float* __restrict__ vp, u16* __restrict__ Vpt)
{
  __shared__ float t[64][65];
  const int b = blockIdx.z, m0 = blockIdx.y << 6, c0 = blockIdx.x << 6;
  const int tid = threadIdx.x;
  const int cc = tid & 63, r4 = tid >> 6;
#pragma unroll
  for (int i = 0; i < 16; ++i) {
    const int m = (i << 2) + r4;
    t[m][cc] = vp[((size_t)((b << 10) + m0 + m)) * CD + c0 + cc];
  }
  __syncthreads();
  const int mm = tid & 63;
#pragma unroll
  for (int i = 0; i < 16; ++i) {
    const int c = (i << 2) + r4;
    Vpt[((size_t)(b * CD + c0 + c) << 10) + m0 + mm] = f2bf(t[mm][c]);
  }
}

// ---------------------------------------------------------------------------
// Fused persistent Sinkhorn v5: round-7 structure + (a) convergence early-exit
// (bitwise-uniform across WGs), (b) fused Et = bf16(z*E)^T write in epilogue.
// ---------------------------------------------------------------------------
__global__ __launch_bounds__(512, 2)
void k_sinkhorn(const float* __restrict__ E, const int* __restrict__ maskI,
                const float* __restrict__ muVal, float* __restrict__ w,
                float* __restrict__ z, float* __restrict__ attn,
                float* __restrict__ part, unsigned* __restrict__ ctrl,
                u16* __restrict__ Et)
{
  const int b = blockIdx.x & 7;
  const int g = blockIdx.x >> 3;       // 0..15
  const int tid = threadIdx.x;
  const int wave = tid >> 6, lane = tid & 63;
  const int m0 = (g << 6) + (wave << 3);
  const float* Eb = E + ((size_t)b << 20);
  float* wb = w + (b << 10);
  unsigned* flagB = ctrl + 64 + (b << 6);

  __shared__ float wS[1024];
  __shared__ __align__(16) char scratch[256 * 72 * 2];  // 36864B: colRed / Et tile
  __shared__ int convF[8];
  float (*colRed)[1024] = (float (*)[1024])scratch;
  u16* etile = (u16*)scratch;
  unsigned* etile32 = (unsigned*)scratch;

  float e[8][16];
#pragma unroll
  for (int r = 0; r < 8; ++r) {
    const float* row = Eb + ((size_t)(m0 + r) << 10) + lane;
#pragma unroll
    for (int j = 0; j < 16; ++j) e[r][j] = row[j << 6];
  }
  float rmask[8];
#pragma unroll
  for (int r = 0; r < 8; ++r)
    rmask[r] = maskI[(b << 10) + m0 + r] ? 1.f : 0.f;
  const float muT = muVal[b];
  const float nuT = 1.0f / (float)NQ + 1e-8f;
  float zr[8];
#pragma unroll
  for (int r = 0; r < 8; ++r) zr[r] = 0.f;

  wS[tid] = 1.0f; wS[tid + 512] = 1.0f;
  float wp0 = 1.0f, wp1 = 1.0f;        // previous w for convergence check
  __syncthreads();

  for (int it = 0; it < 100; ++it) {
    float* partP = part + (size_t)((((it & 1) << 3) + b) << 14);  // [16][1024]
    // u-phase
    float wv[16];
#pragma unroll
    for (int j = 0; j < 16; ++j) wv[j] = wS[lane + (j << 6)];
#pragma unroll
    for (int r = 0; r < 8; ++r) {
      float s = 0.f;
#pragma unroll
      for (int j = 0; j < 16; ++j) s = fmaf(e[r][j], wv[j], s);
      s = wave_reduce_sum(s);
      zr[r] = rmask[r] * (muT / fmaxf(s, 1e-35f));
    }
    // column partials -> LDS per wave
#pragma unroll
    for (int j = 0; j < 16; ++j) {
      float pj = 0.f;
#pragma unroll
      for (int r = 0; r < 8; ++r) pj = fmaf(e[r][j], zr[r], pj);
      colRed[wave][lane + (j << 6)] = pj;
    }
    __syncthreads();
    // reduce 8 waves, publish WG's contiguous 1024-float partial slice
    for (int n = tid; n < 1024; n += 512) {
      float s = 0.f;
#pragma unroll
      for (int w8 = 0; w8 < 8; ++w8) s += colRed[w8][n];
      g_store(partP + (g << 10) + n, s);
    }
    __syncthreads();                       // drains vmcnt: publishes complete
    const unsigned gen = (unsigned)(it + 1);
    if (tid == 0) g_storeu(flagB + g, gen);
    if (wave == 0 && lane < 16) {
      while (g_loadu(flagB + lane) < gen)
        __builtin_amdgcn_s_sleep(1);
    }
    __syncthreads();
    __builtin_amdgcn_fence(__ATOMIC_ACQUIRE, "workgroup");
    // gather -> full w vector; convergence check (identical math in all WGs)
    {
      float s0 = 0.f, s1 = 0.f;
#pragma unroll
      for (int gg = 0; gg < 16; ++gg) {
        s0 += g_load(partP + (gg << 10) + tid);
        s1 += g_load(partP + (gg << 10) + tid + 512);
      }
      const float w0 = nuT / fmaxf(s0, 1e-35f);
      const float w1 = nuT / fmaxf(s1, 1e-35f);
      wS[tid]       = w0;
      wS[tid + 512] = w1;
      const bool bad = (fabsf(w0 - wp0) > 1e-6f * fabsf(w0)) ||
                       (fabsf(w1 - wp1) > 1e-6f * fabsf(w1));
      wp0 = w0; wp1 = w1;
      const unsigned long long anyBad = __ballot(bad);
      if (lane == 0) convF[wave] = (anyBad != 0ull) ? 1 : 0;
    }
    __syncthreads();
    int conv = 1;
#pragma unroll
    for (int w8 = 0; w8 < 8; ++w8) conv &= (convF[w8] == 0);
    if (conv) break;                   // uniform across all WGs (same data/order)
  }

  // epilogue 1: attn + z
  {
    float wv[16];
#pragma unroll
    for (int j = 0; j < 16; ++j) wv[j] = wS[lane + (j << 6)];
#pragma unroll
    for (int r = 0; r < 8; ++r) {
      float s = 0.f;
#pragma unroll
      for (int j = 0; j < 16; ++j) {
        const float ee = e[r][j];
        s += (1.f + EPS_OT * __logf(ee)) * ee * wv[j];
      }
      s = wave_reduce_sum(s);
      if (!lane) {
        const int m = (b << 10) + m0 + r;
        z[m] = zr[r];
        attn[m] = 1048576.0f * zr[r] * s;
      }
    }
    for (int n = tid; n < 1024; n += 512) wb[n] = wS[n];
  }

  // epilogue 2: Et[b][n][m] = bf16(z[m]*E[m][n]) for this WG's 64 m-columns,
  // via LDS transpose tiles of 256 n-rows (stride 72 u16, b128-aligned rows).
  __syncthreads();   // colRed no longer needed
#pragma unroll
  for (int c = 0; c < 4; ++c) {
#pragma unroll
    for (int jj = 0; jj < 4; ++jj) {
      const int j = (c << 2) + jj;
      const int nl = (jj << 6) + lane;          // 0..255
#pragma unroll
      for (int r = 0; r < 8; r += 2)
        etile32[nl * 36 + (wave << 2) + (r >> 1)] =
          pack2bf(e[r][j] * zr[r], e[r + 1][j] * zr[r + 1]);
    }
    __syncthreads();
    if (tid < 256) {
      const float4* src = (const float4*)(etile + tid * 72);   // 144B stride, aligned
      float4* dst = (float4*)(Et + ((((size_t)(b << 10)) + (c << 8) + tid) << 10) + (g << 6));
#pragma unroll
      for (int q = 0; q < 8; ++q) dst[q] = src[q];
    }
    __syncthreads();
  }
}

// ---------------------------------------------------------------------------
extern "C" void kernel_launch(void* const* d_in, const int* in_sizes, int n_in,
                              void* d_out, int out_size, void* d_ws, size_t ws_size,
                              hipStream_t stream)
{
  const float* xq = (const float*)d_in[0];
  const float* xk = (const float*)d_in[1];
  const float* xv = (const float*)d_in[2];
  const void*  maskRaw = d_in[3];
  const float* Wq = (const float*)d_in[4];
  const float* bq = (const float*)d_in[5];
  const float* Wk = (const float*)d_in[6];
  const float* bk = (const float*)d_in[7];
  const float* Wv = (const float*)d_in[8];
  const float* bv = (const float*)d_in[9];
  const float* Wp = (const float*)d_in[10];
  const float* bp = (const float*)d_in[11];

  float* out  = (float*)d_out;
  float* attn = out + (size_t)NQ * B_DIM * CD;

  char* base = (char*)d_ws;
  const size_t OFF_E   = 0;          // E fp32 33.55MB; pre-sim: xqh/xkh/xvh bf16
  const size_t OFF_QB  = 33554432;   // qb fp32; post-l2: part(1MB) + Et(@ +2MB)
  const size_t OFF_KB  = 54525952;   // kb fp32
  const size_t OFF_VP  = 75497472;   // vp fp32; post-vpt: qbh+kbh bf16
  const size_t OFF_VPT = 96468992;   // Vpt bf16 10.49MB
  const size_t OFF_SM  = 106954752;  // weights bf16 + small arrays

  float* E   = (float*)(base + OFF_E);
  u16* xqh   = (u16*)(base + OFF_E);
  u16* xkh   = xqh + (size_t)8192 * CD;
  u16* xvh   = xkh + (size_t)8192 * CD;
  float* qb  = (float*)(base + OFF_QB);
  float* part= (float*)(base + OFF_QB);
  u16* Et    = (u16*)(base + OFF_QB + 2097152);
  float* kb  = (float*)(base + OFF_KB);
  float* vp  = (float*)(base + OFF_VP);
  u16* qbh   = (u16*)(base + OFF_VP);
  u16* kbh   = qbh + (size_t)8192 * CD;
  u16* Vpt   = (u16*)(base + OFF_VPT);
  u16* Wqh   = (u16*)(base + OFF_SM);
  u16* Wkh   = Wqh + CD * CD;
  u16* Ah    = Wkh + CD * CD;
  float* bvp = (float*)(Ah + CD * CD);
  float* z   = bvp + CD;
  float* w   = z + B_DIM * MK;
  int* maskI = (int*)(w + B_DIM * NQ);
  float* muVal = (float*)(maskI + B_DIM * MK);
  unsigned* ctrl = (unsigned*)(muVal + B_DIM);   // [1024]: flags at +64

  k_setup<<<1, 1024, 0, stream>>>(maskRaw, maskI, muVal, w, ctrl);
  k_cvt5<<<dim3(5120, 5), 256, 0, stream>>>(xq, xqh, xk, xkh, xv, xvh,
                                            Wq, Wqh, Wk, Wkh);
  k_combineA<<<dim3(10, 10), 256, 0, stream>>>(Wp, Wv, Ah);
  k_bvp<<<160, 256, 0, stream>>>(Wp, bv, bvp);

  mfma_proj<<<dim3(64, 5, 3), 256, 0, stream>>>(xqh, xkh, xvh, Wqh, Wkh, Ah,
                                                bq, bk, bvp, qb, kb, vp);
  k_vpt<<<dim3(10, 16, 8), 256, 0, stream>>>(vp, Vpt);
  k_l2bf<<<4096, 256, 0, stream>>>(qb, qbh);   // qb|kb contiguous -> qbh|kbh

  mfma_sim<<<dim3(8, 8, 8), 256, 0, stream>>>(kbh, qbh, E);

  {
    void* args[] = {(void*)&E, (void*)&maskI, (void*)&muVal, (void*)&w,
                    (void*)&z, (void*)&attn, (void*)&part, (void*)&ctrl,
                    (void*)&Et};
    hipLaunchCooperativeKernel((void*)k_sinkhorn, dim3(128), dim3(512),
                               args, 0, stream);
  }

  mfma_x<<<dim3(8, 5, 8), 256, 0, stream>>>(Et, Vpt, w, bp, out);
}

// Round 9
// 738.724 us; speedup vs baseline: 1.1432x; 1.1432x over previous
//
#include <hip/hip_runtime.h>
#include <cstdint>
#include <cstddef>

#define B_DIM 8
#define NQ    1024
#define MK    1024
#define CD    640
#define INV_EPS 20.0f
#define EPS_OT  0.05f

typedef unsigned short u16;
typedef __attribute__((ext_vector_type(8))) short bf16x8;
typedef __attribute__((ext_vector_type(4))) float f32x4;

#define GLDS(gp, lp) __builtin_amdgcn_global_load_lds( \
    (const __attribute__((address_space(1))) void*)(gp), \
    (__attribute__((address_space(3))) void*)(lp), 16, 0, 0)

static __device__ __forceinline__ float wave_reduce_sum(float s) {
#pragma unroll
  for (int off = 32; off; off >>= 1) s += __shfl_xor(s, off, 64);
  return s;
}

static __device__ __forceinline__ u16 f2bf(float f) {
  uint32_t u = __float_as_uint(f);
  u += 0x7fff + ((u >> 16) & 1);     // RNE
  return (u16)(u >> 16);
}

// Agent-scope (MALL-coherent, placement-independent) relaxed accesses.
static __device__ __forceinline__ void g_store(float* p, float v) {
  __hip_atomic_store(p, v, __ATOMIC_RELAXED, __HIP_MEMORY_SCOPE_AGENT);
}
static __device__ __forceinline__ float g_load(const float* p) {
  return __hip_atomic_load((float*)p, __ATOMIC_RELAXED, __HIP_MEMORY_SCOPE_AGENT);
}
static __device__ __forceinline__ void g_storeu(unsigned* p, unsigned v) {
  __hip_atomic_store(p, v, __ATOMIC_RELAXED, __HIP_MEMORY_SCOPE_AGENT);
}
static __device__ __forceinline__ unsigned g_loadu(const unsigned* p) {
  return __hip_atomic_load((unsigned*)p, __ATOMIC_RELAXED, __HIP_MEMORY_SCOPE_AGENT);
}

// ---------------------------------------------------------------------------
// Setup: detect mask dtype, build maskI, per-batch mu, w=1, zero ctrl block
// ---------------------------------------------------------------------------
__global__ void k_setup(const void* __restrict__ maskRaw, int* __restrict__ maskI,
                        float* __restrict__ muVal, float* __restrict__ w,
                        unsigned* __restrict__ ctrl)
{
  __shared__ int s_flag;
  __shared__ int s_cnt[B_DIM];
  const int tid = threadIdx.x;
  if (tid == 0) s_flag = 0;
  if (tid < B_DIM) s_cnt[tid] = 0;
  ctrl[tid] = 0u;
  __syncthreads();

  const unsigned char* mb = (const unsigned char*)maskRaw;
  int local = 0;
  for (int i = tid; i < B_DIM * MK; i += 1024)
    if ((i & 3) && mb[i]) local = 1;
  if (local) atomicOr(&s_flag, 1);
  __syncthreads();

  const int isByte = s_flag;
  const int* mi32 = (const int*)maskRaw;
  for (int i = tid; i < B_DIM * MK; i += 1024) {
    int v = isByte ? (int)mb[i] : mi32[i];
    v = v ? 1 : 0;
    maskI[i] = v;
    if (v) atomicAdd(&s_cnt[i >> 10], 1);
  }
  for (int i = tid; i < B_DIM * NQ; i += 1024) w[i] = 1.0f;
  __syncthreads();
  if (tid < B_DIM) {
    float c = (float)s_cnt[tid];
    muVal[tid] = (c > 0.f ? 1.0f / c : 1.0f / (float)MK) + 1e-8f;
  }
}

// ---------------------------------------------------------------------------
// fp32 -> bf16 conversion for xq, xk, xv, Wq, Wk
// ---------------------------------------------------------------------------
__global__ __launch_bounds__(256)
void k_cvt5(const float* __restrict__ x0, u16* __restrict__ d0,
            const float* __restrict__ x1, u16* __restrict__ d1,
            const float* __restrict__ x2, u16* __restrict__ d2,
            const float* __restrict__ x3, u16* __restrict__ d3,
            const float* __restrict__ x4, u16* __restrict__ d4)
{
  const int a = blockIdx.y;
  const float* s; u16* d; int n;
  if      (a == 0) { s = x0; d = d0; n = 8192 * CD; }
  else if (a == 1) { s = x1; d = d1; n = 8192 * CD; }
  else if (a == 2) { s = x2; d = d2; n = 8192 * CD; }
  else if (a == 3) { s = x3; d = d3; n = CD * CD; }
  else             { s = x4; d = d4; n = CD * CD; }
  const int i = (blockIdx.x * 256 + threadIdx.x) * 4;
  if (i >= n) return;
  const float4 v = *(const float4*)(s + i);
  *(ushort4*)(d + i) = make_ushort4(f2bf(v.x), f2bf(v.y), f2bf(v.z), f2bf(v.w));
}

// ---------------------------------------------------------------------------
// Ah = bf16(Wp @ Wv)
// ---------------------------------------------------------------------------
__global__ __launch_bounds__(256)
void k_combineA(const float* __restrict__ Wp, const float* __restrict__ Wv,
                u16* __restrict__ Ah)
{
  __shared__ float Ps[32][68];
  __shared__ float Vs[32][68];
  const int tid = threadIdx.x;
  const int c0 = blockIdx.x << 6, k0 = blockIdx.y << 6;
  const int ty = tid >> 4, tx = tid & 15;
  float acc[4][4];
#pragma unroll
  for (int i = 0; i < 4; ++i)
#pragma unroll
    for (int j = 0; j < 4; ++j) acc[i][j] = 0.f;

  for (int j0 = 0; j0 < CD; j0 += 32) {
    {
      const int c = tid >> 2, j4 = (tid & 3) << 3;
      const float* p = Wp + (size_t)(c0 + c) * CD + j0 + j4;
      float4 u0 = *(const float4*)p, u1 = *(const float4*)(p + 4);
      Ps[j4 + 0][c] = u0.x; Ps[j4 + 1][c] = u0.y; Ps[j4 + 2][c] = u0.z; Ps[j4 + 3][c] = u0.w;
      Ps[j4 + 4][c] = u1.x; Ps[j4 + 5][c] = u1.y; Ps[j4 + 6][c] = u1.z; Ps[j4 + 7][c] = u1.w;
    }
    {
      const int j = tid >> 3, k4 = (tid & 7) << 3;
      const float* p = Wv + (size_t)(j0 + j) * CD + k0 + k4;
      float4 u0 = *(const float4*)p, u1 = *(const float4*)(p + 4);
      *(float4*)&Vs[j][k4] = u0; *(float4*)&Vs[j][k4 + 4] = u1;
    }
    __syncthreads();
#pragma unroll
    for (int j = 0; j < 32; ++j) {
      float a[4], b[4];
      *(float4*)a = *(const float4*)&Ps[j][ty << 2];
      *(float4*)b = *(const float4*)&Vs[j][tx << 2];
#pragma unroll
      for (int i = 0; i < 4; ++i)
#pragma unroll
        for (int jj = 0; jj < 4; ++jj)
          acc[i][jj] = fmaf(a[i], b[jj], acc[i][jj]);
    }
    __syncthreads();
  }
#pragma unroll
  for (int i = 0; i < 4; ++i) {
    *(ushort4*)(Ah + (size_t)(c0 + (ty << 2) + i) * CD + k0 + (tx << 2)) =
      make_ushort4(f2bf(acc[i][0]), f2bf(acc[i][1]), f2bf(acc[i][2]), f2bf(acc[i][3]));
  }
}

// bvp[c] = sum_j Wp[c][j]*bv[j]
__global__ __launch_bounds__(256)
void k_bvp(const float* __restrict__ Wp, const float* __restrict__ bv,
           float* __restrict__ bvp)
{
  const int c = (blockIdx.x << 2) + (threadIdx.x >> 6);
  const int lane = threadIdx.x & 63;
  float s = 0.f;
  for (int j = lane; j < CD; j += 64) s = fmaf(Wp[(size_t)c * CD + j], bv[j], s);
  s = wave_reduce_sum(s);
  if (!lane) bvp[c] = s;
}

// ---------------------------------------------------------------------------
// MFMA NT GEMMs (unchanged, round-5 proven)
// ---------------------------------------------------------------------------
__global__ __launch_bounds__(256)
void mfma_proj(const u16* __restrict__ xqh, const u16* __restrict__ xkh,
               const u16* __restrict__ xvh,
               const u16* __restrict__ Wqh, const u16* __restrict__ Wkh,
               const u16* __restrict__ Ah,
               const float* __restrict__ bq, const float* __restrict__ bk,
               const float* __restrict__ bvp,
               float* __restrict__ qb, float* __restrict__ kb,
               float* __restrict__ vp)
{
  __shared__ u16 As[128 * 32];
  __shared__ u16 Bs[128 * 32];
  const int mode = blockIdx.z;
  const u16* X     = (mode == 0) ? xqh : ((mode == 1) ? xkh : xvh);
  const u16* W     = (mode == 0) ? Wqh : ((mode == 1) ? Wkh : Ah);
  const float* bias= (mode == 0) ? bq  : ((mode == 1) ? bk  : bvp);
  float* outp      = (mode == 0) ? qb  : ((mode == 1) ? kb  : vp);

  const int tid = threadIdx.x, wave = tid >> 6, lane = tid & 63;
  const int row0 = blockIdx.x << 7, col0 = blockIdx.y << 7;

  const int rS = (wave << 5) + (lane >> 2);
  const int pc = lane & 3;
  const int kc0 = pc ^ ((rS >> 1) & 3);
  const int kc1 = pc ^ (((rS + 16) >> 1) & 3);
  const u16* gA0 = X + (size_t)(row0 + rS) * CD + (kc0 << 3);
  const u16* gA1 = X + (size_t)(row0 + rS + 16) * CD + (kc1 << 3);
  const u16* gB0 = W + (size_t)(col0 + rS) * CD + (kc0 << 3);
  const u16* gB1 = W + (size_t)(col0 + rS + 16) * CD + (kc1 << 3);
  u16* lA = As + (wave << 10);
  u16* lB = Bs + (wave << 10);

  const int wm0 = (wave & 1) << 6, wn0 = (wave >> 1) << 6;
  int aOff[4], bOff[4];
#pragma unroll
  for (int t = 0; t < 4; ++t) {
    const int ra = wm0 + (t << 4) + (lane & 15);
    aOff[t] = ra * 32 + (((lane >> 4) ^ ((ra >> 1) & 3)) << 3);
    const int rb = wn0 + (t << 4) + (lane & 15);
    bOff[t] = rb * 32 + (((lane >> 4) ^ ((rb >> 1) & 3)) << 3);
  }
  f32x4 acc[4][4];
#pragma unroll
  for (int i = 0; i < 4; ++i)
#pragma unroll
    for (int j = 0; j < 4; ++j) acc[i][j] = {0.f, 0.f, 0.f, 0.f};

  for (int k0 = 0; k0 < CD; k0 += 32) {
    __syncthreads();
    GLDS(gA0, lA); GLDS(gA1, lA + 512);
    GLDS(gB0, lB); GLDS(gB1, lB + 512);
    gA0 += 32; gA1 += 32; gB0 += 32; gB1 += 32;
    __syncthreads();
    bf16x8 a[4], b[4];
#pragma unroll
    for (int t = 0; t < 4; ++t) {
      a[t] = *(const bf16x8*)(As + aOff[t]);
      b[t] = *(const bf16x8*)(Bs + bOff[t]);
    }
#pragma unroll
    for (int i = 0; i < 4; ++i)
#pragma unroll
      for (int j = 0; j < 4; ++j)
        acc[i][j] = __builtin_amdgcn_mfma_f32_16x16x32_bf16(a[i], b[j], acc[i][j], 0, 0, 0);
  }

  float bv4[4];
  int ccs[4];
#pragma unroll
  for (int j = 0; j < 4; ++j) {
    ccs[j] = col0 + wn0 + (j << 4) + (lane & 15);
    bv4[j] = bias[ccs[j]];
  }
#pragma unroll
  for (int i = 0; i < 4; ++i) {
    const int rbase = row0 + wm0 + (i << 4) + ((lane >> 4) << 2);
#pragma unroll
    for (int r = 0; r < 4; ++r) {
      const int rr = rbase + r;
      const size_t orow = (mode == 0) ? ((size_t)(rr & 7) * NQ + (rr >> 3)) : (size_t)rr;
      float* op = outp + orow * CD;
#pragma unroll
      for (int j = 0; j < 4; ++j)
        op[ccs[j]] = acc[i][j][r] + bv4[j];
    }
  }
}

__global__ __launch_bounds__(256)
void mfma_sim(const u16* __restrict__ kbh, const u16* __restrict__ qbh,
              float* __restrict__ E)
{
  __shared__ u16 As[128 * 32];
  __shared__ u16 Bs[128 * 32];
  const int tid = threadIdx.x, wave = tid >> 6, lane = tid & 63;
  const int b = blockIdx.z;
  const int row0 = blockIdx.x << 7, col0 = blockIdx.y << 7;
  const u16* A = kbh + (size_t)b * MK * CD;
  const u16* B = qbh + (size_t)b * NQ * CD;

  const int rS = (wave << 5) + (lane >> 2);
  const int pc = lane & 3;
  const int kc0 = pc ^ ((rS >> 1) & 3);
  const int kc1 = pc ^ (((rS + 16) >> 1) & 3);
  const u16* gA0 = A + (size_t)(row0 + rS) * CD + (kc0 << 3);
  const u16* gA1 = A + (size_t)(row0 + rS + 16) * CD + (kc1 << 3);
  const u16* gB0 = B + (size_t)(col0 + rS) * CD + (kc0 << 3);
  const u16* gB1 = B + (size_t)(col0 + rS + 16) * CD + (kc1 << 3);
  u16* lA = As + (wave << 10);
  u16* lB = Bs + (wave << 10);

  const int wm0 = (wave & 1) << 6, wn0 = (wave >> 1) << 6;
  int aOff[4], bOff[4];
#pragma unroll
  for (int t = 0; t < 4; ++t) {
    const int ra = wm0 + (t << 4) + (lane & 15);
    aOff[t] = ra * 32 + (((lane >> 4) ^ ((ra >> 1) & 3)) << 3);
    const int rb = wn0 + (t << 4) + (lane & 15);
    bOff[t] = rb * 32 + (((lane >> 4) ^ ((rb >> 1) & 3)) << 3);
  }
  f32x4 acc[4][4];
#pragma unroll
  for (int i = 0; i < 4; ++i)
#pragma unroll
    for (int j = 0; j < 4; ++j) acc[i][j] = {0.f, 0.f, 0.f, 0.f};

  for (int k0 = 0; k0 < CD; k0 += 32) {
    __syncthreads();
    GLDS(gA0, lA); GLDS(gA1, lA + 512);
    GLDS(gB0, lB); GLDS(gB1, lB + 512);
    gA0 += 32; gA1 += 32; gB0 += 32; gB1 += 32;
    __syncthreads();
    bf16x8 a[4], b[4];
#pragma unroll
    for (int t = 0; t < 4; ++t) {
      a[t] = *(const bf16x8*)(As + aOff[t]);
      b[t] = *(const bf16x8*)(Bs + bOff[t]);
    }
#pragma unroll
    for (int i = 0; i < 4; ++i)
#pragma unroll
      for (int j = 0; j < 4; ++j)
        acc[i][j] = __builtin_amdgcn_mfma_f32_16x16x32_bf16(a[i], b[j], acc[i][j], 0, 0, 0);
  }

#pragma unroll
  for (int i = 0; i < 4; ++i) {
    const int rbase = row0 + wm0 + (i << 4) + ((lane >> 4) << 2);
#pragma unroll
    for (int r = 0; r < 4; ++r) {
      const int rr = rbase + r;
      float* erow = E + (((size_t)(b << 10) + rr) << 10);
#pragma unroll
      for (int j = 0; j < 4; ++j) {
        const int cc = col0 + wn0 + (j << 4) + (lane & 15);
        erow[cc] = __expf((acc[i][j][r] - 1.f) * INV_EPS);
      }
    }
  }
}

__global__ __launch_bounds__(256)
void mfma_x(const u16* __restrict__ Et, const u16* __restrict__ Vpt,
            const float* __restrict__ w, const float* __restrict__ bp,
            float* __restrict__ out)
{
  __shared__ u16 As[128 * 32];
  __shared__ u16 Bs[128 * 32];
  const int tid = threadIdx.x, wave = tid >> 6, lane = tid & 63;
  const int b = blockIdx.z;
  const int row0 = blockIdx.x << 7;
  const int col0 = blockIdx.y << 7;
  const u16* A = Et + ((size_t)b << 20);
  const u16* B = Vpt + (size_t)b * CD * MK;

  const int rS = (wave << 5) + (lane >> 2);
  const int pc = lane & 3;
  const int kc0 = pc ^ ((rS >> 1) & 3);
  const int kc1 = pc ^ (((rS + 16) >> 1) & 3);
  const u16* gA0 = A + ((size_t)(row0 + rS) << 10) + (kc0 << 3);
  const u16* gA1 = A + ((size_t)(row0 + rS + 16) << 10) + (kc1 << 3);
  const u16* gB0 = B + ((size_t)(col0 + rS) << 10) + (kc0 << 3);
  const u16* gB1 = B + ((size_t)(col0 + rS + 16) << 10) + (kc1 << 3);
  u16* lA = As + (wave << 10);
  u16* lB = Bs + (wave << 10);

  const int wm0 = (wave & 1) << 6, wn0 = (wave >> 1) << 6;
  int aOff[4], bOff[4];
#pragma unroll
  for (int t = 0; t < 4; ++t) {
    const int ra = wm0 + (t << 4) + (lane & 15);
    aOff[t] = ra * 32 + (((lane >> 4) ^ ((ra >> 1) & 3)) << 3);
    const int rb = wn0 + (t << 4) + (lane & 15);
    bOff[t] = rb * 32 + (((lane >> 4) ^ ((rb >> 1) & 3)) << 3);
  }
  f32x4 acc[4][4];
#pragma unroll
  for (int i = 0; i < 4; ++i)
#pragma unroll
    for (int j = 0; j < 4; ++j) acc[i][j] = {0.f, 0.f, 0.f, 0.f};

  for (int k0 = 0; k0 < MK; k0 += 32) {
    __syncthreads();
    GLDS(gA0, lA); GLDS(gA1, lA + 512);
    GLDS(gB0, lB); GLDS(gB1, lB + 512);
    gA0 += 32; gA1 += 32; gB0 += 32; gB1 += 32;
    __syncthreads();
    bf16x8 a[4], b[4];
#pragma unroll
    for (int t = 0; t < 4; ++t) {
      a[t] = *(const bf16x8*)(As + aOff[t]);
      b[t] = *(const bf16x8*)(Bs + bOff[t]);
    }
#pragma unroll
    for (int i = 0; i < 4; ++i)
#pragma unroll
      for (int j = 0; j < 4; ++j)
        acc[i][j] = __builtin_amdgcn_mfma_f32_16x16x32_bf16(a[i], b[j], acc[i][j], 0, 0, 0);
  }

  float bv4[4];
  int ccs[4];
#pragma unroll
  for (int j = 0; j < 4; ++j) {
    ccs[j] = col0 + wn0 + (j << 4) + (lane & 15);
    bv4[j] = bp[ccs[j]];
  }
#pragma unroll
  for (int i = 0; i < 4; ++i) {
    const int rbase = row0 + wm0 + (i << 4) + ((lane >> 4) << 2);
#pragma unroll
    for (int r = 0; r < 4; ++r) {
      const int rr = rbase + r;
      const float wn = w[(b << 10) + rr];
      float* op = out + ((size_t)rr * 8 + b) * CD;
#pragma unroll
      for (int j = 0; j < 4; ++j)
        op[ccs[j]] = acc[i][j][r] * wn + bv4[j];
    }
  }
}

// ---------------------------------------------------------------------------
// l2norm rows of 640 fp32 -> bf16 output (single launch covers qb|kb)
// ---------------------------------------------------------------------------
__global__ __launch_bounds__(256)
void k_l2bf(const float* __restrict__ X, u16* __restrict__ O)
{
  const int row = (blockIdx.x << 2) + (threadIdx.x >> 6);
  const int lane = threadIdx.x & 63;
  const float2* p2 = (const float2*)(X + (size_t)row * CD);
  float2 v[5];
  float ss = 0.f;
#pragma unroll
  for (int i = 0; i < 5; ++i) {
    v[i] = p2[lane + (i << 6)];
    ss = fmaf(v[i].x, v[i].x, fmaf(v[i].y, v[i].y, ss));
  }
  ss = wave_reduce_sum(ss);
  const float inv = 1.0f / fmaxf(sqrtf(ss), 1e-12f);
  ushort2* o2 = (ushort2*)(O + (size_t)row * CD);
#pragma unroll
  for (int i = 0; i < 5; ++i)
    o2[lane + (i << 6)] = make_ushort2(f2bf(v[i].x * inv), f2bf(v[i].y * inv));
}

// ---------------------------------------------------------------------------
// Transposes: vp -> Vpt bf16 ; z*E -> Et bf16 (separate, full-device kernels)
// ---------------------------------------------------------------------------
__global__ __launch_bounds__(256)
void k_vpt(const float* __restrict__ vp, u16* __restrict__ Vpt)
{
  __shared__ float t[64][65];
  const int b = blockIdx.z, m0 = blockIdx.y << 6, c0 = blockIdx.x << 6;
  const int tid = threadIdx.x;
  const int cc = tid & 63, r4 = tid >> 6;
#pragma unroll
  for (int i = 0; i < 16; ++i) {
    const int m = (i << 2) + r4;
    t[m][cc] = vp[((size_t)((b << 10) + m0 + m)) * CD + c0 + cc];
  }
  __syncthreads();
  const int mm = tid & 63;
#pragma unroll
  for (int i = 0; i < 16; ++i) {
    const int c = (i << 2) + r4;
    Vpt[((size_t)(b * CD + c0 + c) << 10) + m0 + mm] = f2bf(t[mm][c]);
  }
}

__global__ __launch_bounds__(256)
void k_et(const float* __restrict__ E, const float* __restrict__ z,
          u16* __restrict__ Et)
{
  __shared__ float t[64][65];
  const int b = blockIdx.z, m0 = blockIdx.y << 6, n0 = blockIdx.x << 6;
  const int tid = threadIdx.x;
  const int nn = tid & 63, r4 = tid >> 6;
#pragma unroll
  for (int i = 0; i < 16; ++i) {
    const int m = (i << 2) + r4;
    const float zm = z[(b << 10) + m0 + m];
    t[m][nn] = E[(((size_t)((b << 10) + m0 + m)) << 10) + n0 + nn] * zm;
  }
  __syncthreads();
  const int mm = tid & 63;
#pragma unroll
  for (int i = 0; i < 16; ++i) {
    const int n = (i << 2) + r4;
    Et[(((size_t)((b << 10) + n0 + n)) << 10) + m0 + mm] = f2bf(t[mm][n]);
  }
}

// ---------------------------------------------------------------------------
// Fused persistent Sinkhorn (round-7 proven): 128 WGs x 512 thr, 64 E-rows/WG
// in registers. One exchange per iteration: publish partial slice -> per-WG
// flag store (no RMW serialization) -> parallel 16-flag poll -> gather.
// All cross-WG traffic via agent-scope relaxed atomics (G16-safe).
// ---------------------------------------------------------------------------
__global__ __launch_bounds__(512, 2)
void k_sinkhorn(const float* __restrict__ E, const int* __restrict__ maskI,
                const float* __restrict__ muVal, float* __restrict__ w,
                float* __restrict__ z, float* __restrict__ attn,
                float* __restrict__ part, unsigned* __restrict__ ctrl)
{
  const int b = blockIdx.x & 7;        // XCD-affinity swizzle (perf heuristic only)
  const int g = blockIdx.x >> 3;       // 0..15
  const int tid = threadIdx.x;
  const int wave = tid >> 6, lane = tid & 63;
  const int m0 = (g << 6) + (wave << 3);
  const float* Eb = E + ((size_t)b << 20);
  float* wb = w + (b << 10);
  unsigned* flagB = ctrl + 64 + (b << 6);   // 16 flags per batch, 256B stride

  __shared__ float wS[1024];
  __shared__ float colRed[8][1024];

  // load 64 rows into registers
  float e[8][16];
#pragma unroll
  for (int r = 0; r < 8; ++r) {
    const float* row = Eb + ((size_t)(m0 + r) << 10) + lane;
#pragma unroll
    for (int j = 0; j < 16; ++j) e[r][j] = row[j << 6];
  }
  float rmask[8];
#pragma unroll
  for (int r = 0; r < 8; ++r)
    rmask[r] = maskI[(b << 10) + m0 + r] ? 1.f : 0.f;
  const float muT = muVal[b];
  const float nuT = 1.0f / (float)NQ + 1e-8f;
  float zr[8];
#pragma unroll
  for (int r = 0; r < 8; ++r) zr[r] = 0.f;

  wS[tid] = 1.0f; wS[tid + 512] = 1.0f;
  __syncthreads();

  for (int it = 0; it < 100; ++it) {
    // parity double-buffer for partials: barrier separates read(p) / write(p)
    float* partP = part + (size_t)((((it & 1) << 3) + b) << 14);  // [16][1024]
    // u-phase
    float wv[16];
#pragma unroll
    for (int j = 0; j < 16; ++j) wv[j] = wS[lane + (j << 6)];
#pragma unroll
    for (int r = 0; r < 8; ++r) {
      float s = 0.f;
#pragma unroll
      for (int j = 0; j < 16; ++j) s = fmaf(e[r][j], wv[j], s);
      s = wave_reduce_sum(s);
      zr[r] = rmask[r] * (muT / fmaxf(s, 1e-35f));
    }
    // column partials -> LDS per wave
#pragma unroll
    for (int j = 0; j < 16; ++j) {
      float pj = 0.f;
#pragma unroll
      for (int r = 0; r < 8; ++r) pj = fmaf(e[r][j], zr[r], pj);
      colRed[wave][lane + (j << 6)] = pj;
    }
    __syncthreads();
    // reduce 8 waves, publish WG's contiguous 1024-float partial slice
    for (int n = tid; n < 1024; n += 512) {
      float s = 0.f;
#pragma unroll
      for (int w8 = 0; w8 < 8; ++w8) s += colRed[w8][n];
      g_store(partP + (g << 10) + n, s);
    }
    __syncthreads();                       // drains vmcnt: publishes complete
    const unsigned gen = (unsigned)(it + 1);
    if (tid == 0) g_storeu(flagB + g, gen);            // independent flag store
    if (wave == 0 && lane < 16) {                      // parallel 16-flag poll
      while (g_loadu(flagB + lane) < gen)
        __builtin_amdgcn_s_sleep(1);
    }
    __syncthreads();
    __builtin_amdgcn_fence(__ATOMIC_ACQUIRE, "workgroup");  // compiler ordering
    // gather: each thread sums the 16 partials for n=tid and n=tid+512
    {
      float s0 = 0.f, s1 = 0.f;
#pragma unroll
      for (int gg = 0; gg < 16; ++gg) {
        s0 += g_load(partP + (gg << 10) + tid);
        s1 += g_load(partP + (gg << 10) + tid + 512);
      }
      wS[tid]       = nuT / fmaxf(s0, 1e-35f);
      wS[tid + 512] = nuT / fmaxf(s1, 1e-35f);
    }
    __syncthreads();
  }

  // epilogue: attn + z with final z (iter-100 u) and final w (iter-100 v, in wS)
  {
    float wv[16];
#pragma unroll
    for (int j = 0; j < 16; ++j) wv[j] = wS[lane + (j << 6)];
#pragma unroll
    for (int r = 0; r < 8; ++r) {
      float s = 0.f;
#pragma unroll
      for (int j = 0; j < 16; ++j) {
        const float ee = e[r][j];
        s += (1.f + EPS_OT * __logf(ee)) * ee * wv[j];
      }
      s = wave_reduce_sum(s);
      if (!lane) {
        const int m = (b << 10) + m0 + r;
        z[m] = zr[r];
        attn[m] = 1048576.0f * zr[r] * s;
      }
    }
    for (int n = tid; n < 1024; n += 512) wb[n] = wS[n];
  }
}

// ---------------------------------------------------------------------------
extern "C" void kernel_launch(void* const* d_in, const int* in_sizes, int n_in,
                              void* d_out, int out_size, void* d_ws, size_t ws_size,
                              hipStream_t stream)
{
  const float* xq = (const float*)d_in[0];
  const float* xk = (const float*)d_in[1];
  const float* xv = (const float*)d_in[2];
  const void*  maskRaw = d_in[3];
  const float* Wq = (const float*)d_in[4];
  const float* bq = (const float*)d_in[5];
  const float* Wk = (const float*)d_in[6];
  const float* bk = (const float*)d_in[7];
  const float* Wv = (const float*)d_in[8];
  const float* bv = (const float*)d_in[9];
  const float* Wp = (const float*)d_in[10];
  const float* bp = (const float*)d_in[11];

  float* out  = (float*)d_out;
  float* attn = out + (size_t)NQ * B_DIM * CD;

  char* base = (char*)d_ws;
  const size_t OFF_E   = 0;          // E fp32 33.55MB; pre-sim: xqh/xkh/xvh bf16
  const size_t OFF_QB  = 33554432;   // qb fp32; post-l2: part(1MB) + Et(@ +2MB)
  const size_t OFF_KB  = 54525952;   // kb fp32
  const size_t OFF_VP  = 75497472;   // vp fp32; post-vpt: qbh+kbh bf16
  const size_t OFF_VPT = 96468992;   // Vpt bf16 10.49MB
  const size_t OFF_SM  = 106954752;  // weights bf16 + small arrays

  float* E   = (float*)(base + OFF_E);
  u16* xqh   = (u16*)(base + OFF_E);
  u16* xkh   = xqh + (size_t)8192 * CD;
  u16* xvh   = xkh + (size_t)8192 * CD;
  float* qb  = (float*)(base + OFF_QB);
  float* part= (float*)(base + OFF_QB);
  u16* Et    = (u16*)(base + OFF_QB + 2097152);
  float* kb  = (float*)(base + OFF_KB);
  float* vp  = (float*)(base + OFF_VP);
  u16* qbh   = (u16*)(base + OFF_VP);
  u16* kbh   = qbh + (size_t)8192 * CD;
  u16* Vpt   = (u16*)(base + OFF_VPT);
  u16* Wqh   = (u16*)(base + OFF_SM);
  u16* Wkh   = Wqh + CD * CD;
  u16* Ah    = Wkh + CD * CD;
  float* bvp = (float*)(Ah + CD * CD);
  float* z   = bvp + CD;
  float* w   = z + B_DIM * MK;
  int* maskI = (int*)(w + B_DIM * NQ);
  float* muVal = (float*)(maskI + B_DIM * MK);
  unsigned* ctrl = (unsigned*)(muVal + B_DIM);   // [1024]: flags at +64

  k_setup<<<1, 1024, 0, stream>>>(maskRaw, maskI, muVal, w, ctrl);
  k_cvt5<<<dim3(5120, 5), 256, 0, stream>>>(xq, xqh, xk, xkh, xv, xvh,
                                            Wq, Wqh, Wk, Wkh);
  k_combineA<<<dim3(10, 10), 256, 0, stream>>>(Wp, Wv, Ah);
  k_bvp<<<160, 256, 0, stream>>>(Wp, bv, bvp);

  mfma_proj<<<dim3(64, 5, 3), 256, 0, stream>>>(xqh, xkh, xvh, Wqh, Wkh, Ah,
                                                bq, bk, bvp, qb, kb, vp);
  k_vpt<<<dim3(10, 16, 8), 256, 0, stream>>>(vp, Vpt);
  k_l2bf<<<4096, 256, 0, stream>>>(qb, qbh);   // qb|kb contiguous -> qbh|kbh

  mfma_sim<<<dim3(8, 8, 8), 256, 0, stream>>>(kbh, qbh, E);

  {
    void* args[] = {(void*)&E, (void*)&maskI, (void*)&muVal, (void*)&w,
                    (void*)&z, (void*)&attn, (void*)&part, (void*)&ctrl};
    hipLaunchCooperativeKernel((void*)k_sinkhorn, dim3(128), dim3(512),
                               args, 0, stream);
  }

  k_et<<<dim3(16, 16, 8), 256, 0, stream>>>(E, z, Et);
  mfma_x<<<dim3(8, 5, 8), 256, 0, stream>>>(Et, Vpt, w, bp, out);
}

// Round 10
// 727.323 us; speedup vs baseline: 1.1611x; 1.0157x over previous
//
#include <hip/hip_runtime.h>
#include <cstdint>
#include <cstddef>

#define B_DIM 8
#define NQ    1024
#define MK    1024
#define CD    640
#define INV_EPS 20.0f
#define EPS_OT  0.05f

typedef unsigned short u16;
typedef __attribute__((ext_vector_type(8))) short bf16x8;
typedef __attribute__((ext_vector_type(4))) float f32x4;

#define GLDS(gp, lp) __builtin_amdgcn_global_load_lds( \
    (const __attribute__((address_space(1))) void*)(gp), \
    (__attribute__((address_space(3))) void*)(lp), 16, 0, 0)

static __device__ __forceinline__ float wave_reduce_sum(float s) {
#pragma unroll
  for (int off = 32; off; off >>= 1) s += __shfl_xor(s, off, 64);
  return s;
}

static __device__ __forceinline__ u16 f2bf(float f) {
  uint32_t u = __float_as_uint(f);
  u += 0x7fff + ((u >> 16) & 1);     // RNE
  return (u16)(u >> 16);
}

// Agent-scope (MALL-coherent, placement-independent) relaxed accesses.
static __device__ __forceinline__ void g_store(float* p, float v) {
  __hip_atomic_store(p, v, __ATOMIC_RELAXED, __HIP_MEMORY_SCOPE_AGENT);
}
static __device__ __forceinline__ float g_load(const float* p) {
  return __hip_atomic_load((float*)p, __ATOMIC_RELAXED, __HIP_MEMORY_SCOPE_AGENT);
}
static __device__ __forceinline__ void g_storeu(unsigned* p, unsigned v) {
  __hip_atomic_store(p, v, __ATOMIC_RELAXED, __HIP_MEMORY_SCOPE_AGENT);
}
static __device__ __forceinline__ unsigned g_loadu(const unsigned* p) {
  return __hip_atomic_load((unsigned*)p, __ATOMIC_RELAXED, __HIP_MEMORY_SCOPE_AGENT);
}

// ---------------------------------------------------------------------------
// Setup: detect mask dtype, build maskI, per-batch mu, w=1, zero ctrl block
// ---------------------------------------------------------------------------
__global__ void k_setup(const void* __restrict__ maskRaw, int* __restrict__ maskI,
                        float* __restrict__ muVal, float* __restrict__ w,
                        unsigned* __restrict__ ctrl)
{
  __shared__ int s_flag;
  __shared__ int s_cnt[B_DIM];
  const int tid = threadIdx.x;
  if (tid == 0) s_flag = 0;
  if (tid < B_DIM) s_cnt[tid] = 0;
  ctrl[tid] = 0u;
  __syncthreads();

  const unsigned char* mb = (const unsigned char*)maskRaw;
  int local = 0;
  for (int i = tid; i < B_DIM * MK; i += 1024)
    if ((i & 3) && mb[i]) local = 1;
  if (local) atomicOr(&s_flag, 1);
  __syncthreads();

  const int isByte = s_flag;
  const int* mi32 = (const int*)maskRaw;
  for (int i = tid; i < B_DIM * MK; i += 1024) {
    int v = isByte ? (int)mb[i] : mi32[i];
    v = v ? 1 : 0;
    maskI[i] = v;
    if (v) atomicAdd(&s_cnt[i >> 10], 1);
  }
  for (int i = tid; i < B_DIM * NQ; i += 1024) w[i] = 1.0f;
  __syncthreads();
  if (tid < B_DIM) {
    float c = (float)s_cnt[tid];
    muVal[tid] = (c > 0.f ? 1.0f / c : 1.0f / (float)MK) + 1e-8f;
  }
}

// ---------------------------------------------------------------------------
// fp32 -> bf16 conversion for xq, xk, xv, Wq, Wk
// ---------------------------------------------------------------------------
__global__ __launch_bounds__(256)
void k_cvt5(const float* __restrict__ x0, u16* __restrict__ d0,
            const float* __restrict__ x1, u16* __restrict__ d1,
            const float* __restrict__ x2, u16* __restrict__ d2,
            const float* __restrict__ x3, u16* __restrict__ d3,
            const float* __restrict__ x4, u16* __restrict__ d4)
{
  const int a = blockIdx.y;
  const float* s; u16* d; int n;
  if      (a == 0) { s = x0; d = d0; n = 8192 * CD; }
  else if (a == 1) { s = x1; d = d1; n = 8192 * CD; }
  else if (a == 2) { s = x2; d = d2; n = 8192 * CD; }
  else if (a == 3) { s = x3; d = d3; n = CD * CD; }
  else             { s = x4; d = d4; n = CD * CD; }
  const int i = (blockIdx.x * 256 + threadIdx.x) * 4;
  if (i >= n) return;
  const float4 v = *(const float4*)(s + i);
  *(ushort4*)(d + i) = make_ushort4(f2bf(v.x), f2bf(v.y), f2bf(v.z), f2bf(v.w));
}

// ---------------------------------------------------------------------------
// Ah = bf16(Wp @ Wv)
// ---------------------------------------------------------------------------
__global__ __launch_bounds__(256)
void k_combineA(const float* __restrict__ Wp, const float* __restrict__ Wv,
                u16* __restrict__ Ah)
{
  __shared__ float Ps[32][68];
  __shared__ float Vs[32][68];
  const int tid = threadIdx.x;
  const int c0 = blockIdx.x << 6, k0 = blockIdx.y << 6;
  const int ty = tid >> 4, tx = tid & 15;
  float acc[4][4];
#pragma unroll
  for (int i = 0; i < 4; ++i)
#pragma unroll
    for (int j = 0; j < 4; ++j) acc[i][j] = 0.f;

  for (int j0 = 0; j0 < CD; j0 += 32) {
    {
      const int c = tid >> 2, j4 = (tid & 3) << 3;
      const float* p = Wp + (size_t)(c0 + c) * CD + j0 + j4;
      float4 u0 = *(const float4*)p, u1 = *(const float4*)(p + 4);
      Ps[j4 + 0][c] = u0.x; Ps[j4 + 1][c] = u0.y; Ps[j4 + 2][c] = u0.z; Ps[j4 + 3][c] = u0.w;
      Ps[j4 + 4][c] = u1.x; Ps[j4 + 5][c] = u1.y; Ps[j4 + 6][c] = u1.z; Ps[j4 + 7][c] = u1.w;
    }
    {
      const int j = tid >> 3, k4 = (tid & 7) << 3;
      const float* p = Wv + (size_t)(j0 + j) * CD + k0 + k4;
      float4 u0 = *(const float4*)p, u1 = *(const float4*)(p + 4);
      *(float4*)&Vs[j][k4] = u0; *(float4*)&Vs[j][k4 + 4] = u1;
    }
    __syncthreads();
#pragma unroll
    for (int j = 0; j < 32; ++j) {
      float a[4], b[4];
      *(float4*)a = *(const float4*)&Ps[j][ty << 2];
      *(float4*)b = *(const float4*)&Vs[j][tx << 2];
#pragma unroll
      for (int i = 0; i < 4; ++i)
#pragma unroll
        for (int jj = 0; jj < 4; ++jj)
          acc[i][jj] = fmaf(a[i], b[jj], acc[i][jj]);
    }
    __syncthreads();
  }
#pragma unroll
  for (int i = 0; i < 4; ++i) {
    *(ushort4*)(Ah + (size_t)(c0 + (ty << 2) + i) * CD + k0 + (tx << 2)) =
      make_ushort4(f2bf(acc[i][0]), f2bf(acc[i][1]), f2bf(acc[i][2]), f2bf(acc[i][3]));
  }
}

// bvp[c] = sum_j Wp[c][j]*bv[j]
__global__ __launch_bounds__(256)
void k_bvp(const float* __restrict__ Wp, const float* __restrict__ bv,
           float* __restrict__ bvp)
{
  const int c = (blockIdx.x << 2) + (threadIdx.x >> 6);
  const int lane = threadIdx.x & 63;
  float s = 0.f;
  for (int j = lane; j < CD; j += 64) s = fmaf(Wp[(size_t)c * CD + j], bv[j], s);
  s = wave_reduce_sum(s);
  if (!lane) bvp[c] = s;
}

// ---------------------------------------------------------------------------
// MFMA projections. mode 0: qb = perm(xq@Wq^T)+bq ; 1: kb = xk@Wk^T+bk ;
// mode 2: Vpt[b][c][m] = bf16(xv@Ah^T+bvp) written TRANSPOSED directly
// (acc reg r-axis = 4 consecutive m -> ushort4 stores; quads+i cover lines).
// ---------------------------------------------------------------------------
__global__ __launch_bounds__(256)
void mfma_proj(const u16* __restrict__ xqh, const u16* __restrict__ xkh,
               const u16* __restrict__ xvh,
               const u16* __restrict__ Wqh, const u16* __restrict__ Wkh,
               const u16* __restrict__ Ah,
               const float* __restrict__ bq, const float* __restrict__ bk,
               const float* __restrict__ bvp,
               float* __restrict__ qb, float* __restrict__ kb,
               u16* __restrict__ Vpt)
{
  __shared__ u16 As[128 * 32];
  __shared__ u16 Bs[128 * 32];
  const int mode = blockIdx.z;
  const u16* X     = (mode == 0) ? xqh : ((mode == 1) ? xkh : xvh);
  const u16* W     = (mode == 0) ? Wqh : ((mode == 1) ? Wkh : Ah);
  const float* bias= (mode == 0) ? bq  : ((mode == 1) ? bk  : bvp);

  const int tid = threadIdx.x, wave = tid >> 6, lane = tid & 63;
  const int row0 = blockIdx.x << 7, col0 = blockIdx.y << 7;

  const int rS = (wave << 5) + (lane >> 2);
  const int pc = lane & 3;
  const int kc0 = pc ^ ((rS >> 1) & 3);
  const int kc1 = pc ^ (((rS + 16) >> 1) & 3);
  const u16* gA0 = X + (size_t)(row0 + rS) * CD + (kc0 << 3);
  const u16* gA1 = X + (size_t)(row0 + rS + 16) * CD + (kc1 << 3);
  const u16* gB0 = W + (size_t)(col0 + rS) * CD + (kc0 << 3);
  const u16* gB1 = W + (size_t)(col0 + rS + 16) * CD + (kc1 << 3);
  u16* lA = As + (wave << 10);
  u16* lB = Bs + (wave << 10);

  const int wm0 = (wave & 1) << 6, wn0 = (wave >> 1) << 6;
  int aOff[4], bOff[4];
#pragma unroll
  for (int t = 0; t < 4; ++t) {
    const int ra = wm0 + (t << 4) + (lane & 15);
    aOff[t] = ra * 32 + (((lane >> 4) ^ ((ra >> 1) & 3)) << 3);
    const int rb = wn0 + (t << 4) + (lane & 15);
    bOff[t] = rb * 32 + (((lane >> 4) ^ ((rb >> 1) & 3)) << 3);
  }
  f32x4 acc[4][4];
#pragma unroll
  for (int i = 0; i < 4; ++i)
#pragma unroll
    for (int j = 0; j < 4; ++j) acc[i][j] = {0.f, 0.f, 0.f, 0.f};

  for (int k0 = 0; k0 < CD; k0 += 32) {
    __syncthreads();
    GLDS(gA0, lA); GLDS(gA1, lA + 512);
    GLDS(gB0, lB); GLDS(gB1, lB + 512);
    gA0 += 32; gA1 += 32; gB0 += 32; gB1 += 32;
    __syncthreads();
    bf16x8 a[4], b[4];
#pragma unroll
    for (int t = 0; t < 4; ++t) {
      a[t] = *(const bf16x8*)(As + aOff[t]);
      b[t] = *(const bf16x8*)(Bs + bOff[t]);
    }
#pragma unroll
    for (int i = 0; i < 4; ++i)
#pragma unroll
      for (int j = 0; j < 4; ++j)
        acc[i][j] = __builtin_amdgcn_mfma_f32_16x16x32_bf16(a[i], b[j], acc[i][j], 0, 0, 0);
  }

  float bv4[4];
  int ccs[4];
#pragma unroll
  for (int j = 0; j < 4; ++j) {
    ccs[j] = col0 + wn0 + (j << 4) + (lane & 15);
    bv4[j] = bias[ccs[j]];
  }
  if (mode == 2) {
    // transposed bf16 write: Vpt[(b*CD+c)*1024 + m], 4 consecutive m per store
#pragma unroll
    for (int i = 0; i < 4; ++i) {
      const int rbase = row0 + wm0 + (i << 4) + ((lane >> 4) << 2);  // global m-row
      const int bb = rbase >> 10, mloc = rbase & 1023;               // no straddle: rbase%4==0
#pragma unroll
      for (int j = 0; j < 4; ++j) {
        ushort4 o = make_ushort4(f2bf(acc[i][j][0] + bv4[j]), f2bf(acc[i][j][1] + bv4[j]),
                                 f2bf(acc[i][j][2] + bv4[j]), f2bf(acc[i][j][3] + bv4[j]));
        *(ushort4*)(Vpt + (((size_t)(bb * CD + ccs[j])) << 10) + mloc) = o;
      }
    }
  } else {
    float* outp = (mode == 0) ? qb : kb;
#pragma unroll
    for (int i = 0; i < 4; ++i) {
      const int rbase = row0 + wm0 + (i << 4) + ((lane >> 4) << 2);
#pragma unroll
      for (int r = 0; r < 4; ++r) {
        const int rr = rbase + r;
        const size_t orow = (mode == 0) ? ((size_t)(rr & 7) * NQ + (rr >> 3)) : (size_t)rr;
        float* op = outp + orow * CD;
#pragma unroll
        for (int j = 0; j < 4; ++j)
          op[ccs[j]] = acc[i][j][r] + bv4[j];
      }
    }
  }
}

__global__ __launch_bounds__(256)
void mfma_sim(const u16* __restrict__ kbh, const u16* __restrict__ qbh,
              float* __restrict__ E)
{
  __shared__ u16 As[128 * 32];
  __shared__ u16 Bs[128 * 32];
  const int tid = threadIdx.x, wave = tid >> 6, lane = tid & 63;
  const int b = blockIdx.z;
  const int row0 = blockIdx.x << 7, col0 = blockIdx.y << 7;
  const u16* A = kbh + (size_t)b * MK * CD;
  const u16* B = qbh + (size_t)b * NQ * CD;

  const int rS = (wave << 5) + (lane >> 2);
  const int pc = lane & 3;
  const int kc0 = pc ^ ((rS >> 1) & 3);
  const int kc1 = pc ^ (((rS + 16) >> 1) & 3);
  const u16* gA0 = A + (size_t)(row0 + rS) * CD + (kc0 << 3);
  const u16* gA1 = A + (size_t)(row0 + rS + 16) * CD + (kc1 << 3);
  const u16* gB0 = B + (size_t)(col0 + rS) * CD + (kc0 << 3);
  const u16* gB1 = B + (size_t)(col0 + rS + 16) * CD + (kc1 << 3);
  u16* lA = As + (wave << 10);
  u16* lB = Bs + (wave << 10);

  const int wm0 = (wave & 1) << 6, wn0 = (wave >> 1) << 6;
  int aOff[4], bOff[4];
#pragma unroll
  for (int t = 0; t < 4; ++t) {
    const int ra = wm0 + (t << 4) + (lane & 15);
    aOff[t] = ra * 32 + (((lane >> 4) ^ ((ra >> 1) & 3)) << 3);
    const int rb = wn0 + (t << 4) + (lane & 15);
    bOff[t] = rb * 32 + (((lane >> 4) ^ ((rb >> 1) & 3)) << 3);
  }
  f32x4 acc[4][4];
#pragma unroll
  for (int i = 0; i < 4; ++i)
#pragma unroll
    for (int j = 0; j < 4; ++j) acc[i][j] = {0.f, 0.f, 0.f, 0.f};

  for (int k0 = 0; k0 < CD; k0 += 32) {
    __syncthreads();
    GLDS(gA0, lA); GLDS(gA1, lA + 512);
    GLDS(gB0, lB); GLDS(gB1, lB + 512);
    gA0 += 32; gA1 += 32; gB0 += 32; gB1 += 32;
    __syncthreads();
    bf16x8 a[4], b[4];
#pragma unroll
    for (int t = 0; t < 4; ++t) {
      a[t] = *(const bf16x8*)(As + aOff[t]);
      b[t] = *(const bf16x8*)(Bs + bOff[t]);
    }
#pragma unroll
    for (int i = 0; i < 4; ++i)
#pragma unroll
      for (int j = 0; j < 4; ++j)
        acc[i][j] = __builtin_amdgcn_mfma_f32_16x16x32_bf16(a[i], b[j], acc[i][j], 0, 0, 0);
  }

#pragma unroll
  for (int i = 0; i < 4; ++i) {
    const int rbase = row0 + wm0 + (i << 4) + ((lane >> 4) << 2);
#pragma unroll
    for (int r = 0; r < 4; ++r) {
      const int rr = rbase + r;
      float* erow = E + (((size_t)(b << 10) + rr) << 10);
#pragma unroll
      for (int j = 0; j < 4; ++j) {
        const int cc = col0 + wn0 + (j << 4) + (lane & 15);
        erow[cc] = __expf((acc[i][j][r] - 1.f) * INV_EPS);
      }
    }
  }
}

// ---------------------------------------------------------------------------
// mfma_x: 64(n) x 128(c) tiles, grid (16,5,8)=640 blocks (2.5/CU for latency
// hiding; the 128x128 version had 320 blocks = 1.25/CU, staging-latency-bound)
// ---------------------------------------------------------------------------
__global__ __launch_bounds__(256)
void mfma_x(const u16* __restrict__ Et, const u16* __restrict__ Vpt,
            const float* __restrict__ w, const float* __restrict__ bp,
            float* __restrict__ out)
{
  __shared__ u16 As[64 * 32];    // 4KB
  __shared__ u16 Bs[128 * 32];   // 8KB
  const int tid = threadIdx.x, wave = tid >> 6, lane = tid & 63;
  const int b = blockIdx.z;
  const int row0 = blockIdx.x << 6;   // n
  const int col0 = blockIdx.y << 7;   // c
  const u16* A = Et + ((size_t)b << 20);
  const u16* B = Vpt + (size_t)b * CD * MK;

  // staging: A 64 rows = 1 GLDS/wave (16 rows each); B 128 rows = 2 GLDS/wave
  const int rA = (wave << 4) + (lane >> 2);        // 0..63
  const int pc = lane & 3;
  const int kcA  = pc ^ ((rA >> 1) & 3);
  const int kcB1 = pc ^ (((rA + 64) >> 1) & 3);
  const u16* gA0 = A + ((size_t)(row0 + rA) << 10) + (kcA << 3);
  const u16* gB0 = B + ((size_t)(col0 + rA) << 10) + (kcA << 3);
  const u16* gB1 = B + ((size_t)(col0 + rA + 64) << 10) + (kcB1 << 3);
  u16* lA  = As + (wave << 9);            // wave's 16 rows x 32 u16
  u16* lB0 = Bs + (wave << 9);
  u16* lB1 = Bs + 2048 + (wave << 9);

  // fragments: a spans 64 rows (4 frags); b spans this wave's 32 cols (2 frags)
  int aOff[4], bOff[2];
#pragma unroll
  for (int t = 0; t < 4; ++t) {
    const int ra = (t << 4) + (lane & 15);
    aOff[t] = ra * 32 + (((lane >> 4) ^ ((ra >> 1) & 3)) << 3);
  }
#pragma unroll
  for (int t = 0; t < 2; ++t) {
    const int rb = (wave << 5) + (t << 4) + (lane & 15);
    bOff[t] = rb * 32 + (((lane >> 4) ^ ((rb >> 1) & 3)) << 3);
  }
  f32x4 acc[4][2];
#pragma unroll
  for (int i = 0; i < 4; ++i)
#pragma unroll
    for (int j = 0; j < 2; ++j) acc[i][j] = {0.f, 0.f, 0.f, 0.f};

  for (int k0 = 0; k0 < MK; k0 += 32) {
    __syncthreads();
    GLDS(gA0, lA); GLDS(gB0, lB0); GLDS(gB1, lB1);
    gA0 += 32; gB0 += 32; gB1 += 32;
    __syncthreads();
    bf16x8 a[4], b[2];
#pragma unroll
    for (int t = 0; t < 4; ++t) a[t] = *(const bf16x8*)(As + aOff[t]);
#pragma unroll
    for (int t = 0; t < 2; ++t) b[t] = *(const bf16x8*)(Bs + bOff[t]);
#pragma unroll
    for (int i = 0; i < 4; ++i)
#pragma unroll
      for (int j = 0; j < 2; ++j)
        acc[i][j] = __builtin_amdgcn_mfma_f32_16x16x32_bf16(a[i], b[j], acc[i][j], 0, 0, 0);
  }

  float bv2[2];
  int ccs[2];
#pragma unroll
  for (int j = 0; j < 2; ++j) {
    ccs[j] = col0 + (wave << 5) + (j << 4) + (lane & 15);
    bv2[j] = bp[ccs[j]];
  }
#pragma unroll
  for (int i = 0; i < 4; ++i) {
    const int rbase = row0 + (i << 4) + ((lane >> 4) << 2);
#pragma unroll
    for (int r = 0; r < 4; ++r) {
      const int rr = rbase + r;               // n index
      const float wn = w[(b << 10) + rr];
      float* op = out + ((size_t)rr * 8 + b) * CD;
#pragma unroll
      for (int j = 0; j < 2; ++j)
        op[ccs[j]] = acc[i][j][r] * wn + bv2[j];
    }
  }
}

// ---------------------------------------------------------------------------
// l2norm rows of 640 fp32 -> bf16 output (single launch covers qb|kb)
// ---------------------------------------------------------------------------
__global__ __launch_bounds__(256)
void k_l2bf(const float* __restrict__ X, u16* __restrict__ O)
{
  const int row = (blockIdx.x << 2) + (threadIdx.x >> 6);
  const int lane = threadIdx.x & 63;
  const float2* p2 = (const float2*)(X + (size_t)row * CD);
  float2 v[5];
  float ss = 0.f;
#pragma unroll
  for (int i = 0; i < 5; ++i) {
    v[i] = p2[lane + (i << 6)];
    ss = fmaf(v[i].x, v[i].x, fmaf(v[i].y, v[i].y, ss));
  }
  ss = wave_reduce_sum(ss);
  const float inv = 1.0f / fmaxf(sqrtf(ss), 1e-12f);
  ushort2* o2 = (ushort2*)(O + (size_t)row * CD);
#pragma unroll
  for (int i = 0; i < 5; ++i)
    o2[lane + (i << 6)] = make_ushort2(f2bf(v[i].x * inv), f2bf(v[i].y * inv));
}

// ---------------------------------------------------------------------------
// Et transpose: z*E -> Et bf16 (full-device, bandwidth-bound)
// ---------------------------------------------------------------------------
__global__ __launch_bounds__(256)
void k_et(const float* __restrict__ E, const float* __restrict__ z,
          u16* __restrict__ Et)
{
  __shared__ float t[64][65];
  const int b = blockIdx.z, m0 = blockIdx.y << 6, n0 = blockIdx.x << 6;
  const int tid = threadIdx.x;
  const int nn = tid & 63, r4 = tid >> 6;
#pragma unroll
  for (int i = 0; i < 16; ++i) {
    const int m = (i << 2) + r4;
    const float zm = z[(b << 10) + m0 + m];
    t[m][nn] = E[(((size_t)((b << 10) + m0 + m)) << 10) + n0 + nn] * zm;
  }
  __syncthreads();
  const int mm = tid & 63;
#pragma unroll
  for (int i = 0; i < 16; ++i) {
    const int n = (i << 2) + r4;
    Et[(((size_t)((b << 10) + n0 + n)) << 10) + m0 + mm] = f2bf(t[mm][n]);
  }
}

// ---------------------------------------------------------------------------
// Fused persistent Sinkhorn (round-7 proven): 128 WGs x 512 thr, 64 E-rows/WG
// in registers. One exchange per iteration: publish partial slice -> per-WG
// flag store (no RMW serialization) -> parallel 16-flag poll -> gather.
// All cross-WG traffic via agent-scope relaxed atomics (G16-safe).
// ---------------------------------------------------------------------------
__global__ __launch_bounds__(512, 2)
void k_sinkhorn(const float* __restrict__ E, const int* __restrict__ maskI,
                const float* __restrict__ muVal, float* __restrict__ w,
                float* __restrict__ z, float* __restrict__ attn,
                float* __restrict__ part, unsigned* __restrict__ ctrl)
{
  const int b = blockIdx.x & 7;        // XCD-affinity swizzle (perf heuristic only)
  const int g = blockIdx.x >> 3;       // 0..15
  const int tid = threadIdx.x;
  const int wave = tid >> 6, lane = tid & 63;
  const int m0 = (g << 6) + (wave << 3);
  const float* Eb = E + ((size_t)b << 20);
  float* wb = w + (b << 10);
  unsigned* flagB = ctrl + 64 + (b << 6);   // 16 flags per batch, 256B stride

  __shared__ float wS[1024];
  __shared__ float colRed[8][1024];

  // load 64 rows into registers
  float e[8][16];
#pragma unroll
  for (int r = 0; r < 8; ++r) {
    const float* row = Eb + ((size_t)(m0 + r) << 10) + lane;
#pragma unroll
    for (int j = 0; j < 16; ++j) e[r][j] = row[j << 6];
  }
  float rmask[8];
#pragma unroll
  for (int r = 0; r < 8; ++r)
    rmask[r] = maskI[(b << 10) + m0 + r] ? 1.f : 0.f;
  const float muT = muVal[b];
  const float nuT = 1.0f / (float)NQ + 1e-8f;
  float zr[8];
#pragma unroll
  for (int r = 0; r < 8; ++r) zr[r] = 0.f;

  wS[tid] = 1.0f; wS[tid + 512] = 1.0f;
  __syncthreads();

  for (int it = 0; it < 100; ++it) {
    // parity double-buffer for partials: barrier separates read(p) / write(p)
    float* partP = part + (size_t)((((it & 1) << 3) + b) << 14);  // [16][1024]
    // u-phase
    float wv[16];
#pragma unroll
    for (int j = 0; j < 16; ++j) wv[j] = wS[lane + (j << 6)];
#pragma unroll
    for (int r = 0; r < 8; ++r) {
      float s = 0.f;
#pragma unroll
      for (int j = 0; j < 16; ++j) s = fmaf(e[r][j], wv[j], s);
      s = wave_reduce_sum(s);
      zr[r] = rmask[r] * (muT / fmaxf(s, 1e-35f));
    }
    // column partials -> LDS per wave
#pragma unroll
    for (int j = 0; j < 16; ++j) {
      float pj = 0.f;
#pragma unroll
      for (int r = 0; r < 8; ++r) pj = fmaf(e[r][j], zr[r], pj);
      colRed[wave][lane + (j << 6)] = pj;
    }
    __syncthreads();
    // reduce 8 waves, publish WG's contiguous 1024-float partial slice
    for (int n = tid; n < 1024; n += 512) {
      float s = 0.f;
#pragma unroll
      for (int w8 = 0; w8 < 8; ++w8) s += colRed[w8][n];
      g_store(partP + (g << 10) + n, s);
    }
    __syncthreads();                       // drains vmcnt: publishes complete
    const unsigned gen = (unsigned)(it + 1);
    if (tid == 0) g_storeu(flagB + g, gen);            // independent flag store
    if (wave == 0 && lane < 16) {                      // parallel 16-flag poll
      while (g_loadu(flagB + lane) < gen)
        __builtin_amdgcn_s_sleep(1);
    }
    __syncthreads();
    __builtin_amdgcn_fence(__ATOMIC_ACQUIRE, "workgroup");  // compiler ordering
    // gather: each thread sums the 16 partials for n=tid and n=tid+512
    {
      float s0 = 0.f, s1 = 0.f;
#pragma unroll
      for (int gg = 0; gg < 16; ++gg) {
        s0 += g_load(partP + (gg << 10) + tid);
        s1 += g_load(partP + (gg << 10) + tid + 512);
      }
      wS[tid]       = nuT / fmaxf(s0, 1e-35f);
      wS[tid + 512] = nuT / fmaxf(s1, 1e-35f);
    }
    __syncthreads();
  }

  // epilogue: attn + z with final z (iter-100 u) and final w (iter-100 v, in wS)
  {
    float wv[16];
#pragma unroll
    for (int j = 0; j < 16; ++j) wv[j] = wS[lane + (j << 6)];
#pragma unroll
    for (int r = 0; r < 8; ++r) {
      float s = 0.f;
#pragma unroll
      for (int j = 0; j < 16; ++j) {
        const float ee = e[r][j];
        s += (1.f + EPS_OT * __logf(ee)) * ee * wv[j];
      }
      s = wave_reduce_sum(s);
      if (!lane) {
        const int m = (b << 10) + m0 + r;
        z[m] = zr[r];
        attn[m] = 1048576.0f * zr[r] * s;
      }
    }
    for (int n = tid; n < 1024; n += 512) wb[n] = wS[n];
  }
}

// ---------------------------------------------------------------------------
extern "C" void kernel_launch(void* const* d_in, const int* in_sizes, int n_in,
                              void* d_out, int out_size, void* d_ws, size_t ws_size,
                              hipStream_t stream)
{
  const float* xq = (const float*)d_in[0];
  const float* xk = (const float*)d_in[1];
  const float* xv = (const float*)d_in[2];
  const void*  maskRaw = d_in[3];
  const float* Wq = (const float*)d_in[4];
  const float* bq = (const float*)d_in[5];
  const float* Wk = (const float*)d_in[6];
  const float* bk = (const float*)d_in[7];
  const float* Wv = (const float*)d_in[8];
  const float* bv = (const float*)d_in[9];
  const float* Wp = (const float*)d_in[10];
  const float* bp = (const float*)d_in[11];

  float* out  = (float*)d_out;
  float* attn = out + (size_t)NQ * B_DIM * CD;

  char* base = (char*)d_ws;
  const size_t OFF_E   = 0;          // E fp32 33.55MB; pre-sim: xqh/xkh/xvh bf16
  const size_t OFF_QB  = 33554432;   // qb fp32; post-l2: part(1MB) + Et(@ +2MB)
  const size_t OFF_KB  = 54525952;   // kb fp32
  const size_t OFF_VP  = 75497472;   // qbh+kbh bf16 (post-l2bf)
  const size_t OFF_VPT = 96468992;   // Vpt bf16 10.49MB
  const size_t OFF_SM  = 106954752;  // weights bf16 + small arrays

  float* E   = (float*)(base + OFF_E);
  u16* xqh   = (u16*)(base + OFF_E);
  u16* xkh   = xqh + (size_t)8192 * CD;
  u16* xvh   = xkh + (size_t)8192 * CD;
  float* qb  = (float*)(base + OFF_QB);
  float* part= (float*)(base + OFF_QB);
  u16* Et    = (u16*)(base + OFF_QB + 2097152);
  float* kb  = (float*)(base + OFF_KB);
  u16* qbh   = (u16*)(base + OFF_VP);
  u16* kbh   = qbh + (size_t)8192 * CD;
  u16* Vpt   = (u16*)(base + OFF_VPT);
  u16* Wqh   = (u16*)(base + OFF_SM);
  u16* Wkh   = Wqh + CD * CD;
  u16* Ah    = Wkh + CD * CD;
  float* bvp = (float*)(Ah + CD * CD);
  float* z   = bvp + CD;
  float* w   = z + B_DIM * MK;
  int* maskI = (int*)(w + B_DIM * NQ);
  float* muVal = (float*)(maskI + B_DIM * MK);
  unsigned* ctrl = (unsigned*)(muVal + B_DIM);   // [1024]: flags at +64

  k_setup<<<1, 1024, 0, stream>>>(maskRaw, maskI, muVal, w, ctrl);
  k_cvt5<<<dim3(5120, 5), 256, 0, stream>>>(xq, xqh, xk, xkh, xv, xvh,
                                            Wq, Wqh, Wk, Wkh);
  k_combineA<<<dim3(10, 10), 256, 0, stream>>>(Wp, Wv, Ah);
  k_bvp<<<160, 256, 0, stream>>>(Wp, bv, bvp);

  mfma_proj<<<dim3(64, 5, 3), 256, 0, stream>>>(xqh, xkh, xvh, Wqh, Wkh, Ah,
                                                bq, bk, bvp, qb, kb, Vpt);
  k_l2bf<<<4096, 256, 0, stream>>>(qb, qbh);   // qb|kb contiguous -> qbh|kbh

  mfma_sim<<<dim3(8, 8, 8), 256, 0, stream>>>(kbh, qbh, E);

  {
    void* args[] = {(void*)&E, (void*)&maskI, (void*)&muVal, (void*)&w,
                    (void*)&z, (void*)&attn, (void*)&part, (void*)&ctrl};
    hipLaunchCooperativeKernel((void*)k_sinkhorn, dim3(128), dim3(512),
                               args, 0, stream);
  }

  k_et<<<dim3(16, 16, 8), 256, 0, stream>>>(E, z, Et);
  mfma_x<<<dim3(16, 5, 8), 256, 0, stream>>>(Et, Vpt, w, bp, out);
}